// Round 14
// baseline (103.215 us; speedup 1.0000x reference)
//
#include <hip/hip_runtime.h>

#define NGT   32
#define MAXA  2048          // n_ac = 1384 here; LDS arrays sized for < 4096
#define EPSF  1e-5f
#define GTAC_BIT (1 << 20)
#define NTHR  512
#define NWAVE (NTHR / 64)
#define APT   3             // ceil(n_ac / NTHR) for n_ac <= 1536
#define JB    4             // staging width (R14: 8 -> 4 to kill scratch spills)

// Correctly-rounded f32 divide for normal-range inputs (Markstein, 2 corrections).
// b in [1e-5, ~3.3], a in [0,1]: all intermediates normal -> bit-identical to
// IEEE RN division (numpy). No VCC serialization (unlike div_scale/div_fmas).
__device__ __forceinline__ float fdiv_rn(float a, float b) {
    float y0 = __builtin_amdgcn_rcpf(b);
    float e  = fmaf(-b, y0, 1.0f);
    float y1 = fmaf(e, y0, y0);
    float q0 = a * y1;
    float r0 = fmaf(-b, q0, a);
    float q1 = fmaf(r0, y1, q0);
    float r1 = fmaf(-b, q1, a);
    return fmaf(r1, y1, q1);
}

// R14 = R12 with staging width 4 instead of 8. The 8-wide arrays introduced
// in R10 caused persistent scratch spills (+22MB WRITE, +9MB FETCH, ~21
// dwords/thread) at the allocator's chosen 64 VGPR. 4-wide halves live array
// state (~20 ints) to fit without spilling while keeping the ILP that made
// R10 faster than the flat loop.
__global__ __launch_bounds__(NTHR, 4) void rpn_fused(
    const float* __restrict__ bx_gt,     // (B, 32, 4)
    const float* __restrict__ ac_val,    // (n_ac, 4)
    const float* __restrict__ rand_pos,  // (B, n_ac)
    const float* __restrict__ rand_neg,  // (B, n_ac)
    float* __restrict__ out,             // (B, n_ac, 10)
    int n_ac)
{
    #pragma clang fp contract(off)   // match numpy rounding: no cross-statement FMA
    const int b = blockIdx.x, tid = threadIdx.x;
    const int w = tid >> 6, lane = tid & 63;

    __shared__ int   s_pack[MAXA];       // (v<<5)|(31-bgt)  [+GTAC_BIT after B]
    __shared__ int   s_wk[NGT * NWAVE];  // per-wave column-key maxes
    __shared__ int   s_c[NWAVE * 2];     // per-wave fg/bg partials
    __shared__ float s_th[2];
    __shared__ float s_gt[NGT * 4];      // epilogue only (phase A uses s_loads)
    __shared__ float s_o[NTHR * 11];     // staged output, [anchor][k] 10->11 pad

    if (tid < NGT * 4) s_gt[tid] = bx_gt[(size_t)b * NGT * 4 + tid];

    // wave-uniform GT base -> scalar loads; no DS in hot loop
    const float4* __restrict__ gtp = (const float4*)(bx_gt + (size_t)b * NGT * 4);

    // ---- Phase A ----
    float ax0[APT], ax1[APT], ax2[APT], ax3[APT], area[APT];
    float rnd_p[APT], rnd_n[APT];
    int   rkey[APT];
    #pragma unroll
    for (int r = 0; r < APT; ++r) {
        const int ac = min(r * NTHR + tid, n_ac - 1);   // clamped (max-idempotent)
        const float4 av = ((const float4*)ac_val)[ac];
        ax0[r] = av.x; ax1[r] = av.y; ax2[r] = av.z; ax3[r] = av.w;
        area[r] = (av.z - av.x) * (av.w - av.y);
        rnd_p[r] = rand_pos[(size_t)b * n_ac + ac];     // cold-HBM prefetch;
        rnd_n[r] = rand_neg[(size_t)b * n_ac + ac];     // consumed in phase C
        rkey[r] = -1;
    }

    #pragma unroll
    for (int gb = 0; gb < NGT / JB; ++gb) {
        int ck[JB];
        #pragma unroll
        for (int j = 0; j < JB; ++j) ck[j] = 0;

        #pragma unroll
        for (int r = 0; r < APT; ++r) {
            const int akey = 4095 - min(r * NTHR + tid, n_ac - 1);

            // stage 1: JB independent intersection / denominator chains
            float num[JB], den[JB];
            #pragma unroll
            for (int j = 0; j < JB; ++j) {
                const int g = gb * JB + j;
                const float4 g4 = gtp[g];                        // uniform -> s_load
                const float area_g = (g4.z - g4.x) * (g4.w - g4.y);
                float ih = fmaxf(fminf(ax2[r], g4.z) - fmaxf(ax0[r], g4.x), 0.0f);
                float iw = fmaxf(fminf(ax3[r], g4.w) - fmaxf(ax1[r], g4.y), 0.0f);
                float inter = ih * iw;
                num[j] = inter;
                den[j] = (area[r] + area_g - inter) + EPSF;      // numpy assoc order
            }
            // stage 2: JB independent correctly-rounded divides
            int v[JB];
            #pragma unroll
            for (int j = 0; j < JB; ++j)
                v[j] = (int)(fdiv_rn(num[j], den[j]) * 10000.0f); // trunc == astype(i32)
            // stage 3: key updates (row keys tree-merged)
            int rk[JB];
            #pragma unroll
            for (int j = 0; j < JB; ++j) {
                rk[j] = (v[j] << 5) | (31 - (gb * JB + j));      // tie -> first g
                ck[j] = max(ck[j], (v[j] << 12) | akey);         // tie -> min a
            }
            rkey[r] = max(rkey[r], max(max(rk[0], rk[1]), max(rk[2], rk[3])));
        }
        // wave-reduce this g-block's column keys
        #pragma unroll
        for (int j = 0; j < JB; ++j) {
            int k = ck[j];
            #pragma unroll
            for (int off = 32; off >= 1; off >>= 1)
                k = max(k, __shfl_xor(k, off, 64));
            if (lane == 0) s_wk[(gb * JB + j) * NWAVE + w] = k;
        }
    }

    int cf = 0, cb = 0;
    #pragma unroll
    for (int r = 0; r < APT; ++r) {
        const int a = r * NTHR + tid;
        if (a < n_ac) {
            s_pack[a] = rkey[r];
            const int vmax = rkey[r] >> 5;
            cf += (vmax >= 5000);
            cb += (vmax < 3000);
        }
    }
    #pragma unroll
    for (int off = 32; off >= 1; off >>= 1) {
        cf += __shfl_xor(cf, off, 64);
        cb += __shfl_xor(cb, off, 64);
    }
    if (lane == 0) { s_c[w*2] = cf; s_c[w*2+1] = cb; }
    __syncthreads();

    // ---- Phase B: wave 0 finalizes ----
    if (w == 0) {
        int valid = 0, a = 0;
        if (lane < NGT) {
            int key = 0;
            #pragma unroll
            for (int ww = 0; ww < NWAVE; ++ww) key = max(key, s_wk[lane*NWAVE + ww]);
            int v = key >> 12;
            a = 4095 - (key & 4095);
            valid = (v >= 100);                  // POS_TH_GTAC
        }
        int avs = valid ? a : (0x10000 + lane);  // unique sentinel when invalid
        bool dup = false;
        #pragma unroll
        for (int gp = 0; gp < NGT; ++gp) {
            int o = __shfl(avs, gp, 64);
            if (gp < lane && o == avs) dup = true;
        }
        const bool contrib = valid && !dup;
        int rm = 0x7FFF;
        if (contrib) rm = s_pack[a] >> 5;
        unsigned long long m1 = __ballot(contrib && rm < 5000); // gtac-only pos
        unsigned long long m2 = __ballot(contrib && rm < 3000); // neg -> pos fix
        if (contrib) atomicOr(&s_pack[a], GTAC_BIT);
        if (lane == 0) {
            int cff = __popcll(m1), cbb = -__popcll(m2);
            #pragma unroll
            for (int ww = 0; ww < NWAVE; ++ww) { cff += s_c[ww*2]; cbb += s_c[ww*2+1]; }
            s_th[0] = 128.0f / ((float)cff + 1e-6f);
            s_th[1] = 128.0f / ((float)cbb + 1e-6f);
        }
    }
    __syncthreads();

    // ---- Phase C: epilogue + coalesced write ----
    const float th_pos = s_th[0], th_neg = s_th[1];
    #pragma unroll
    for (int r = 0; r < APT; ++r) {
        const int a = r * NTHR + tid;
        if (a < n_ac) {
            const int p = s_pack[a];
            const bool gtac = (p & GTAC_BIT) != 0;
            const int rm = (p >> 5) & 0x7FFF;    // masks GTAC_BIT>>5
            const int bg = 31 - (p & 31);
            const bool pos = (rm >= 5000) || gtac;
            const bool neg = !pos && (rm < 3000);

            const float4 avv = ((const float4*)ac_val)[a];   // L2-warm reload (keeps
            const float a0 = avv.x, a1 = avv.y, a2 = avv.z, a3 = avv.w; // ax[] dead)

            float o0, o1, o2, o3, o4, o5, o6, o7;
            if (pos) {
                float g0 = s_gt[bg*4+0], g1 = s_gt[bg*4+1];
                float g2 = s_gt[bg*4+2], g3 = s_gt[bg*4+3];
                o0 = g0; o1 = g1; o2 = g2; o3 = g3;
                float hr = fmaxf(a2 - a0, EPSF);
                float wr = fmaxf(a3 - a1, EPSF);
                float ycr = a0 + 0.5f * (a2 - a0);
                float xcr = a1 + 0.5f * (a3 - a1);
                float hl = g2 - g0, wl = g3 - g1;
                float ycl = g0 + 0.5f * hl;
                float xcl = g1 + 0.5f * wl;
                o4 = fminf(fmaxf((xcl - xcr) / wr, -10.0f), 10.0f);
                o5 = fminf(fmaxf((ycl - ycr) / hr, -10.0f), 10.0f);
                o6 = fminf(fmaxf(logf(wl / wr), -10.0f), 10.0f);
                o7 = fminf(fmaxf(logf(hl / hr), -10.0f), 10.0f);
            } else {
                float t = neg ? -2.0f : -1.0f;
                o0 = o1 = o2 = o3 = t;
                o4 = o5 = o6 = o7 = 0.0f;        // bx_safe == anchor => delta 0
            }
            const float o8 = (pos && rnd_p[r] < th_pos) ? 1.0f : 0.0f;
            const float o9 = (neg && rnd_n[r] < th_neg) ? 1.0f : 0.0f;

            float* so = &s_o[tid * 11];          // stride 11: 2 lanes/bank (free)
            so[0] = o0; so[1] = o1; so[2] = o2; so[3] = o3; so[4] = o4;
            so[5] = o5; so[6] = o6; so[7] = o7; so[8] = o8; so[9] = o9;
        }
        __syncthreads();

        const int na_blk = min(NTHR, n_ac - r * NTHR);
        if (na_blk > 0) {
            const int nd = na_blk * 10;
            float* dst = out + ((size_t)b * n_ac + (size_t)r * NTHR) * 10;
            #pragma unroll
            for (int m = 0; m < 10; ++m) {
                const int idx = m * NTHR + tid;
                if (idx < nd) {
                    const int al = idx / 10, k = idx - al * 10;
                    dst[idx] = s_o[al * 11 + k]; // ~consecutive addrs across lanes
                }
            }
        }
        __syncthreads();   // s_o reused next round
    }
}

extern "C" void kernel_launch(void* const* d_in, const int* in_sizes, int n_in,
                              void* d_out, int out_size, void* d_ws, size_t ws_size,
                              hipStream_t stream) {
    const float* bx_gt    = (const float*)d_in[0];
    const float* ac_val   = (const float*)d_in[1];
    const float* rand_pos = (const float*)d_in[2];
    const float* rand_neg = (const float*)d_in[3];
    float* out = (float*)d_out;

    const int n_ac = in_sizes[1] / 4;       // (n_ac, 4)
    const int B    = in_sizes[2] / n_ac;    // rand_pos is (B, n_ac)

    rpn_fused<<<B, NTHR, 0, stream>>>(bx_gt, ac_val, rand_pos, rand_neg, out, n_ac);
}

// Round 15
// 99.870 us; speedup vs baseline: 1.0335x; 1.0335x over previous
//
#include <hip/hip_runtime.h>

#define NGT   32
#define MAXA  2048          // n_ac = 1384 here; LDS arrays sized for < 4096
#define EPSF  1e-5f
#define GTAC_BIT (1 << 20)
#define NTHR  512
#define NWAVE (NTHR / 64)
#define APT   3             // ceil(n_ac / NTHR) for n_ac <= 1536
#define JB    4             // staging width

// Correctly-rounded f32 divide for normal-range inputs (Markstein, 2 corrections).
// b in [1e-5, ~3.3], a in [0,1]: all intermediates normal -> bit-identical to
// IEEE RN division (numpy). No VCC serialization (unlike div_scale/div_fmas).
__device__ __forceinline__ float fdiv_rn(float a, float b) {
    float y0 = __builtin_amdgcn_rcpf(b);
    float e  = fmaf(-b, y0, 1.0f);
    float y1 = fmaf(e, y0, y0);
    float q0 = a * y1;
    float r0 = fmaf(-b, q0, a);
    float q1 = fmaf(r0, y1, q0);
    float r1 = fmaf(-b, q1, a);
    return fmaf(r1, y1, q1);
}

// R15 = R14 + ONE change: gb loop NOT unrolled (#pragma unroll 1).
// Phase A's fully-unrolled text (~3000 instr, 20-30KB) was at/above the 32KB
// per-CU I-cache; an I-fetch stall is the only hypothesis consistent with the
// ~42us kernel invariant across occupancy (10-68%), DS-free reductions,
// Markstein div, and staging width. Rolled loop = ~3KB hot text, I-cache
// resident across all 8 iterations.
__global__ __launch_bounds__(NTHR, 4) void rpn_fused(
    const float* __restrict__ bx_gt,     // (B, 32, 4)
    const float* __restrict__ ac_val,    // (n_ac, 4)
    const float* __restrict__ rand_pos,  // (B, n_ac)
    const float* __restrict__ rand_neg,  // (B, n_ac)
    float* __restrict__ out,             // (B, n_ac, 10)
    int n_ac)
{
    #pragma clang fp contract(off)   // match numpy rounding: no cross-statement FMA
    const int b = blockIdx.x, tid = threadIdx.x;
    const int w = tid >> 6, lane = tid & 63;

    __shared__ int   s_pack[MAXA];       // (v<<5)|(31-bgt)  [+GTAC_BIT after B]
    __shared__ int   s_wk[NGT * NWAVE];  // per-wave column-key maxes
    __shared__ int   s_c[NWAVE * 2];     // per-wave fg/bg partials
    __shared__ float s_th[2];
    __shared__ float s_gt[NGT * 4];      // epilogue only (phase A uses s_loads)
    __shared__ float s_o[NTHR * 11];     // staged output, [anchor][k] 10->11 pad

    if (tid < NGT * 4) s_gt[tid] = bx_gt[(size_t)b * NGT * 4 + tid];

    // wave-uniform GT base -> scalar loads; no DS in hot loop
    const float4* __restrict__ gtp = (const float4*)(bx_gt + (size_t)b * NGT * 4);

    // ---- Phase A ----
    float ax0[APT], ax1[APT], ax2[APT], ax3[APT], area[APT];
    float rnd_p[APT], rnd_n[APT];
    int   rkey[APT];
    #pragma unroll
    for (int r = 0; r < APT; ++r) {
        const int ac = min(r * NTHR + tid, n_ac - 1);   // clamped (max-idempotent)
        const float4 av = ((const float4*)ac_val)[ac];
        ax0[r] = av.x; ax1[r] = av.y; ax2[r] = av.z; ax3[r] = av.w;
        area[r] = (av.z - av.x) * (av.w - av.y);
        rnd_p[r] = rand_pos[(size_t)b * n_ac + ac];     // cold-HBM prefetch;
        rnd_n[r] = rand_neg[(size_t)b * n_ac + ac];     // consumed in phase C
        rkey[r] = -1;
    }

    #pragma unroll 1   // ROLLED: keep phase-A hot text small (I-cache resident)
    for (int gb = 0; gb < NGT / JB; ++gb) {
        int ck[JB];
        #pragma unroll
        for (int j = 0; j < JB; ++j) ck[j] = 0;

        #pragma unroll
        for (int r = 0; r < APT; ++r) {
            const int akey = 4095 - min(r * NTHR + tid, n_ac - 1);

            // stage 1: JB independent intersection / denominator chains
            float num[JB], den[JB];
            #pragma unroll
            for (int j = 0; j < JB; ++j) {
                const int g = gb * JB + j;
                const float4 g4 = gtp[g];                        // uniform -> s_load
                const float area_g = (g4.z - g4.x) * (g4.w - g4.y);
                float ih = fmaxf(fminf(ax2[r], g4.z) - fmaxf(ax0[r], g4.x), 0.0f);
                float iw = fmaxf(fminf(ax3[r], g4.w) - fmaxf(ax1[r], g4.y), 0.0f);
                float inter = ih * iw;
                num[j] = inter;
                den[j] = (area[r] + area_g - inter) + EPSF;      // numpy assoc order
            }
            // stage 2: JB independent correctly-rounded divides
            int v[JB];
            #pragma unroll
            for (int j = 0; j < JB; ++j)
                v[j] = (int)(fdiv_rn(num[j], den[j]) * 10000.0f); // trunc == astype(i32)
            // stage 3: key updates (row keys tree-merged)
            int rk[JB];
            #pragma unroll
            for (int j = 0; j < JB; ++j) {
                rk[j] = (v[j] << 5) | (31 - (gb * JB + j));      // tie -> first g
                ck[j] = max(ck[j], (v[j] << 12) | akey);         // tie -> min a
            }
            rkey[r] = max(rkey[r], max(max(rk[0], rk[1]), max(rk[2], rk[3])));
        }
        // wave-reduce this g-block's column keys
        #pragma unroll
        for (int j = 0; j < JB; ++j) {
            int k = ck[j];
            #pragma unroll
            for (int off = 32; off >= 1; off >>= 1)
                k = max(k, __shfl_xor(k, off, 64));
            if (lane == 0) s_wk[(gb * JB + j) * NWAVE + w] = k;
        }
    }

    int cf = 0, cb = 0;
    #pragma unroll
    for (int r = 0; r < APT; ++r) {
        const int a = r * NTHR + tid;
        if (a < n_ac) {
            s_pack[a] = rkey[r];
            const int vmax = rkey[r] >> 5;
            cf += (vmax >= 5000);
            cb += (vmax < 3000);
        }
    }
    #pragma unroll
    for (int off = 32; off >= 1; off >>= 1) {
        cf += __shfl_xor(cf, off, 64);
        cb += __shfl_xor(cb, off, 64);
    }
    if (lane == 0) { s_c[w*2] = cf; s_c[w*2+1] = cb; }
    __syncthreads();

    // ---- Phase B: wave 0 finalizes ----
    if (w == 0) {
        int valid = 0, a = 0;
        if (lane < NGT) {
            int key = 0;
            #pragma unroll
            for (int ww = 0; ww < NWAVE; ++ww) key = max(key, s_wk[lane*NWAVE + ww]);
            int v = key >> 12;
            a = 4095 - (key & 4095);
            valid = (v >= 100);                  // POS_TH_GTAC
        }
        int avs = valid ? a : (0x10000 + lane);  // unique sentinel when invalid
        bool dup = false;
        #pragma unroll
        for (int gp = 0; gp < NGT; ++gp) {
            int o = __shfl(avs, gp, 64);
            if (gp < lane && o == avs) dup = true;
        }
        const bool contrib = valid && !dup;
        int rm = 0x7FFF;
        if (contrib) rm = s_pack[a] >> 5;
        unsigned long long m1 = __ballot(contrib && rm < 5000); // gtac-only pos
        unsigned long long m2 = __ballot(contrib && rm < 3000); // neg -> pos fix
        if (contrib) atomicOr(&s_pack[a], GTAC_BIT);
        if (lane == 0) {
            int cff = __popcll(m1), cbb = -__popcll(m2);
            #pragma unroll
            for (int ww = 0; ww < NWAVE; ++ww) { cff += s_c[ww*2]; cbb += s_c[ww*2+1]; }
            s_th[0] = 128.0f / ((float)cff + 1e-6f);
            s_th[1] = 128.0f / ((float)cbb + 1e-6f);
        }
    }
    __syncthreads();

    // ---- Phase C: epilogue + coalesced write ----
    const float th_pos = s_th[0], th_neg = s_th[1];
    #pragma unroll
    for (int r = 0; r < APT; ++r) {
        const int a = r * NTHR + tid;
        if (a < n_ac) {
            const int p = s_pack[a];
            const bool gtac = (p & GTAC_BIT) != 0;
            const int rm = (p >> 5) & 0x7FFF;    // masks GTAC_BIT>>5
            const int bg = 31 - (p & 31);
            const bool pos = (rm >= 5000) || gtac;
            const bool neg = !pos && (rm < 3000);

            const float4 avv = ((const float4*)ac_val)[a];   // L2-warm reload (keeps
            const float a0 = avv.x, a1 = avv.y, a2 = avv.z, a3 = avv.w; // ax[] dead)

            float o0, o1, o2, o3, o4, o5, o6, o7;
            if (pos) {
                float g0 = s_gt[bg*4+0], g1 = s_gt[bg*4+1];
                float g2 = s_gt[bg*4+2], g3 = s_gt[bg*4+3];
                o0 = g0; o1 = g1; o2 = g2; o3 = g3;
                float hr = fmaxf(a2 - a0, EPSF);
                float wr = fmaxf(a3 - a1, EPSF);
                float ycr = a0 + 0.5f * (a2 - a0);
                float xcr = a1 + 0.5f * (a3 - a1);
                float hl = g2 - g0, wl = g3 - g1;
                float ycl = g0 + 0.5f * hl;
                float xcl = g1 + 0.5f * wl;
                o4 = fminf(fmaxf((xcl - xcr) / wr, -10.0f), 10.0f);
                o5 = fminf(fmaxf((ycl - ycr) / hr, -10.0f), 10.0f);
                o6 = fminf(fmaxf(logf(wl / wr), -10.0f), 10.0f);
                o7 = fminf(fmaxf(logf(hl / hr), -10.0f), 10.0f);
            } else {
                float t = neg ? -2.0f : -1.0f;
                o0 = o1 = o2 = o3 = t;
                o4 = o5 = o6 = o7 = 0.0f;        // bx_safe == anchor => delta 0
            }
            const float o8 = (pos && rnd_p[r] < th_pos) ? 1.0f : 0.0f;
            const float o9 = (neg && rnd_n[r] < th_neg) ? 1.0f : 0.0f;

            float* so = &s_o[tid * 11];          // stride 11: 2 lanes/bank (free)
            so[0] = o0; so[1] = o1; so[2] = o2; so[3] = o3; so[4] = o4;
            so[5] = o5; so[6] = o6; so[7] = o7; so[8] = o8; so[9] = o9;
        }
        __syncthreads();

        const int na_blk = min(NTHR, n_ac - r * NTHR);
        if (na_blk > 0) {
            const int nd = na_blk * 10;
            float* dst = out + ((size_t)b * n_ac + (size_t)r * NTHR) * 10;
            #pragma unroll
            for (int m = 0; m < 10; ++m) {
                const int idx = m * NTHR + tid;
                if (idx < nd) {
                    const int al = idx / 10, k = idx - al * 10;
                    dst[idx] = s_o[al * 11 + k]; // ~consecutive addrs across lanes
                }
            }
        }
        __syncthreads();   // s_o reused next round
    }
}

extern "C" void kernel_launch(void* const* d_in, const int* in_sizes, int n_in,
                              void* d_out, int out_size, void* d_ws, size_t ws_size,
                              hipStream_t stream) {
    const float* bx_gt    = (const float*)d_in[0];
    const float* ac_val   = (const float*)d_in[1];
    const float* rand_pos = (const float*)d_in[2];
    const float* rand_neg = (const float*)d_in[3];
    float* out = (float*)d_out;

    const int n_ac = in_sizes[1] / 4;       // (n_ac, 4)
    const int B    = in_sizes[2] / n_ac;    // rand_pos is (B, n_ac)

    rpn_fused<<<B, NTHR, 0, stream>>>(bx_gt, ac_val, rand_pos, rand_neg, out, n_ac);
}